// Round 15
// baseline (189.712 us; speedup 1.0000x reference)
//
#include <hip/hip_runtime.h>

#define NE 8
#define HW 128
#define OUT_HW 384
#define C1 64
#define C2 32
#define C3 9

typedef __attribute__((ext_vector_type(4))) float f32x4;
typedef __attribute__((ext_vector_type(8))) short bf16x8s;
typedef __attribute__((ext_vector_type(2))) unsigned u32x2;

// Prepacked conv1 weights, bf16: [e][oc=64][tap=32 (25 valid, rest 0)]
__device__ __align__(16) unsigned short g_w1b[NE * C1 * 32];
// Prepacked conv2 weights, bf16: [e][koff(ky*3+kx)][oc=32][ic=64]
__device__ __align__(16) unsigned short g_w2b[NE * 9 * C2 * C1];
// Prepacked conv3 weights, bf16: [e][koff][oc=16 (9 valid)][ic=32]
__device__ __align__(16) unsigned short g_w3b[NE * 9 * 16 * 32];

__device__ __forceinline__ unsigned short f2bf(float f) {
    unsigned u = __builtin_bit_cast(unsigned, f);
    u += 0x7fffu + ((u >> 16) & 1u);          // round-nearest-even
    return (unsigned short)(u >> 16);
}

// Packed f32x2 -> bf16x2 (RNE), 1 VALU inst.  No builtin on gfx950 (T12/m240).
__device__ __forceinline__ unsigned cvt_pk_bf16(float lo, float hi) {
    unsigned r;
    asm("v_cvt_pk_bf16_f32 %0, %1, %2" : "=v"(r) : "v"(lo), "v"(hi));
    return r;
}

__global__ void repack_weights_kernel(const float* __restrict__ w1,
                                      const float* __restrict__ w2,
                                      const float* __restrict__ w3) {
    int i = blockIdx.x * 256 + threadIdx.x;
    const int n2 = NE * C2 * C1 * 9;          // 36864
    const int n1 = NE * C1 * 32;              // 16384
    const int n3 = NE * 9 * 16 * 32;          // 36864
    if (i < n2) {
        // source: [e][oc][ic][ky][kx] -> dest [e][koff][oc][ic]
        int e = i / (C2 * C1 * 9);
        int r = i - e * (C2 * C1 * 9);
        int oc = r / (C1 * 9); r -= oc * (C1 * 9);
        int ic = r / 9;
        int koff = r - ic * 9;
        g_w2b[((e * 9 + koff) * C2 + oc) * C1 + ic] = f2bf(w2[i]);
    } else if (i < n2 + n1) {
        int j = i - n2;                        // [e][oc][tap]
        int tap = j & 31;
        int eoc = j >> 5;                      // e*64+oc
        float v = (tap < 25) ? w1[eoc * 25 + tap] : 0.f;
        g_w1b[j] = f2bf(v);
    } else if (i < n2 + n1 + n3) {
        int j = i - n2 - n1;
        int e = j / (9 * 16 * 32);
        int r = j - e * (9 * 16 * 32);
        int koff = r / 512; r -= koff * 512;
        int oc = r / 32;
        int ic = r - oc * 32;
        float v = 0.f;
        if (oc < C3) v = w3[((e * C3 + oc) * 32 + ic) * 9 + koff];
        g_w3b[((e * 9 + koff) * 16 + oc) * 32 + ic] = f2bf(v);
    }
}

// tanh(x) = 1 - 2/(1+e^{2x}); inf-safe both directions.  5 VALU (2 trans).
__device__ __forceinline__ float fast_tanh(float x) {
    float u = __builtin_amdgcn_exp2f(x * 2.88539008f);   // e^{2x}
    return 1.0f - 2.0f * __builtin_amdgcn_rcpf(1.0f + u);
}

__launch_bounds__(512, 6)
__global__ void espcn_fused_kernel(const float* __restrict__ x,
                                   const int* __restrict__ ci,
                                   const float* __restrict__ b1,
                                   const float* __restrict__ b2,
                                   const float* __restrict__ b3,
                                   float* __restrict__ out) {
    // LDS pool 51200 B -> 3 blocks/CU (24 waves).  Split-K conv2: h1s holds
    // ONE 32-ic half at a time (conv1 runs twice, conv2 accumulates in regs).
    //   region A [0,25600):     imc 400x64B      live 0.5 -> 1B (both conv1 passes)
    //                           h2b 324x64B      live 2B -> 3   (alias)
    //   region B [25600,51200): xs  24x24 f32    live 0 -> 0.5  (alias, head)
    //                           h1s 400x64B      live 1A -> 2B
    //                           outT 48x52 f32   live 3 -> 4    (alias)
    __shared__ __align__(16) char ldsp[51200];
    char* imc         = ldsp;
    char* h2b         = ldsp;
    char* h1s         = ldsp + 25600;
    float (*xs)[24]   = (float(*)[24])(ldsp + 25600);
    float (*outT)[52] = (float(*)[52])(ldsp + 25600);

    const int tx = blockIdx.x, ty = blockIdx.y, b = blockIdx.z;
    const int R0 = ty * 16, C0 = tx * 16;
    // Block-uniform (SGPR) interior predicate: all halos in-image -> skip bounds.
    const bool interior = (tx >= 1) && (tx <= 6) && (ty >= 1) && (ty <= 6);
    int e = ci[b];
    e = __builtin_amdgcn_readfirstlane(e);
    const int t = threadIdx.x;                 // 0..511
    const int lane = t & 63, wave = t >> 6;    // 8 waves
    const int g = lane >> 4, r16 = lane & 15;

    // ---- phase 0: stage x patch rows [R0-4, R0+20), cols [C0-4, C0+20) ----
    #pragma unroll
    for (int it = 0; it < 2; ++it) {
        int idx = it * 512 + t;
        if (idx < 576) {
            int ii = idx / 24, jj = idx - ii * 24;
            int gy = R0 - 4 + ii, gx = C0 - 4 + jj;
            float v = 0.f;
            if (interior || ((unsigned)gy < (unsigned)HW && (unsigned)gx < (unsigned)HW))
                v = x[(b * HW + gy) * HW + gx];
            xs[ii][jj] = v;
        }
    }
    __syncthreads();

    // ---- phase 0.5: im2col 400 px x 16 tap-pairs.  w = t&15 is loop-invariant. ----
    {
        const int w = t & 15, pr = t >> 4;      // pr 0..31
        int t0 = 2 * w;     if (t0 > 24) t0 = 24;
        int t1 = 2 * w + 1; if (t1 > 24) t1 = 24;
        const int dy0 = t0 / 5, dx0 = t0 - 5 * (t0 / 5);
        const int dy1 = t1 / 5, dx1 = t1 - 5 * (t1 / 5);
        const bool v0 = (2 * w) < 25, v1 = (2 * w + 1) < 25;
        const int swz = (w * 4) ^ ((pr & 3) << 4);   // p&3 == pr&3 (32|p-step)
        #pragma unroll
        for (int it = 0; it < 13; ++it) {
            int p = it * 32 + pr;
            if (p < 400) {
                int i = p / 20, j = p - i * 20;
                float f0 = v0 ? xs[i + dy0][j + dx0] : 0.f;
                float f1 = v1 ? xs[i + dy1][j + dx1] : 0.f;
                *(unsigned*)(imc + p * 64 + swz) = cvt_pk_bf16(f0, f1);
            }
        }
    }
    __syncthreads();

    // ---- conv2 state (accumulated across both ic-halves) ----
    const unsigned short* w2e = g_w2b + e * 9 * C2 * C1;
    const bool has2 = (wave + 16) < 21;
    const int pt0 = wave, pt1 = wave + 8, pt2 = has2 ? wave + 16 : wave;
    int rb[3][9];
    {
        int pts[3] = {pt0, pt1, pt2};
        #pragma unroll
        for (int s3 = 0; s3 < 3; ++s3) {
            int px = pts[s3] * 16 + r16; if (px > 323) px = 323;
            int r = px / 18, c = px - r * 18;
            int ab = r * 20 + c;
            #pragma unroll
            for (int k = 0; k < 9; ++k) {
                int ap = ab + (k / 3) * 20 + (k % 3);
                rb[s3][k] = (ap << 6) | ((ap & 3) << 4);   // 64B rows now
            }
        }
    }
    f32x4 a00 = {0.f,0.f,0.f,0.f}, a01 = {0.f,0.f,0.f,0.f};
    f32x4 a10 = {0.f,0.f,0.f,0.f}, a11 = {0.f,0.f,0.f,0.f};
    f32x4 a20 = {0.f,0.f,0.f,0.f}, a21 = {0.f,0.f,0.f,0.f};

    // ---- phases 1A/2A and 1B/2B: conv1 half -> conv2 partial-K accumulate ----
    #pragma unroll
    for (int half = 0; half < 2; ++half) {
        // conv1 pass: this half's 32 oc (2 oc-tiles), 25 px-tiles over 8 waves.
        {
            const unsigned short* w1e = g_w1b + e * C1 * 32;
            const int octile = wave & 1, ptg = wave >> 1;
            const int ocg = half * 32 + octile * 16;           // half-global oc base
            bf16x8s W = *(const bf16x8s*)(w1e + (ocg + r16) * 32 + g * 8);
            f32x4 bias4 = *(const f32x4*)(b1 + e * C1 + ocg + g * 4);
            const int imcb = r16 * 64 + ((g * 16) ^ ((r16 & 3) << 4));
            const int h1b = (r16 << 6) + ((octile * 32 + g * 8) ^ ((r16 & 3) << 4));
            #pragma unroll
            for (int k = 0; k < 7; ++k) {
                int pt = ptg + 4 * k;
                if (pt < 25) {
                    bf16x8s I = *(const bf16x8s*)(imc + pt * 1024 + imcb);
                    f32x4 acc = {0.f, 0.f, 0.f, 0.f};
                    acc = __builtin_amdgcn_mfma_f32_16x16x32_bf16(W, I, acc, 0, 0, 0);
                    float s0 = fast_tanh(acc[0] + bias4[0]);
                    float s1 = fast_tanh(acc[1] + bias4[1]);
                    float s2 = fast_tanh(acc[2] + bias4[2]);
                    float s3 = fast_tanh(acc[3] + bias4[3]);
                    if (!interior) {
                        int p = pt * 16 + r16;
                        int i = p / 20, j = p - i * 20;
                        int gy = R0 - 2 + i, gx = C0 - 2 + j;
                        bool in = ((unsigned)gy < (unsigned)HW) && ((unsigned)gx < (unsigned)HW);
                        if (!in) { s0 = 0.f; s1 = 0.f; s2 = 0.f; s3 = 0.f; }
                    }
                    u32x2 hv = { cvt_pk_bf16(s0, s1), cvt_pk_bf16(s2, s3) };
                    *(u32x2*)(h1s + h1b + pt * 1024) = hv;     // 16 rows x 64B per tile
                }
            }
        }
        __syncthreads();

        // conv2 partial: K = 9 koff x 32 ic (this half), accumulate into regs.
        {
            const int icb = g * 16;
            const int wB = r16 * C1 + half * 32 + g * 8;
            #pragma unroll
            for (int koff = 0; koff < 9; ++koff) {
                const unsigned short* wp = w2e + koff * (C2 * C1);
                bf16x8s B0 = *(const bf16x8s*)(wp + wB);
                bf16x8s B1 = *(const bf16x8s*)(wp + wB + 16 * C1);
                bf16x8s A0 = *(const bf16x8s*)(h1s + (rb[0][koff] ^ icb));
                bf16x8s A1 = *(const bf16x8s*)(h1s + (rb[1][koff] ^ icb));
                a00 = __builtin_amdgcn_mfma_f32_16x16x32_bf16(B0, A0, a00, 0, 0, 0);
                a01 = __builtin_amdgcn_mfma_f32_16x16x32_bf16(B1, A0, a01, 0, 0, 0);
                a10 = __builtin_amdgcn_mfma_f32_16x16x32_bf16(B0, A1, a10, 0, 0, 0);
                a11 = __builtin_amdgcn_mfma_f32_16x16x32_bf16(B1, A1, a11, 0, 0, 0);
                if (has2) {
                    bf16x8s A2 = *(const bf16x8s*)(h1s + (rb[2][koff] ^ icb));
                    a20 = __builtin_amdgcn_mfma_f32_16x16x32_bf16(B0, A2, a20, 0, 0, 0);
                    a21 = __builtin_amdgcn_mfma_f32_16x16x32_bf16(B1, A2, a21, 0, 0, 0);
                }
            }
        }
        __syncthreads();
    }

    // ---- conv2 epilogue: bias+tanh -> h2b (aliases imc; imc now dead) ----
    {
        const float* b2e = b2 + e * C2;
        f32x4 bias0 = *(const f32x4*)(b2e + g * 4);
        f32x4 bias1 = *(const f32x4*)(b2e + 16 + g * 4);
        const int wb0 = (g * 8) ^ ((r16 & 3) << 4);        // px&3 == r16&3
        const int wb1 = (32 + g * 8) ^ ((r16 & 3) << 4);
        #pragma unroll
        for (int s3 = 0; s3 < 3; ++s3) {
            int pt = (s3 == 0) ? pt0 : (s3 == 1) ? pt1 : pt2;
            f32x4 aa0 = (s3 == 0) ? a00 : (s3 == 1) ? a10 : a20;
            f32x4 aa1 = (s3 == 0) ? a01 : (s3 == 1) ? a11 : a21;
            int px = pt * 16 + r16;
            bool wvalid = (px < 324) && (s3 != 2 || has2);
            if (wvalid) {
                float u0 = fast_tanh(aa0[0] + bias0[0]);
                float u1 = fast_tanh(aa0[1] + bias0[1]);
                float u2 = fast_tanh(aa0[2] + bias0[2]);
                float u3 = fast_tanh(aa0[3] + bias0[3]);
                float v0 = fast_tanh(aa1[0] + bias1[0]);
                float v1 = fast_tanh(aa1[1] + bias1[1]);
                float v2 = fast_tanh(aa1[2] + bias1[2]);
                float v3 = fast_tanh(aa1[3] + bias1[3]);
                if (!interior) {
                    int y = px / 18, xx = px - y * 18;
                    int gy = R0 - 1 + y, gx = C0 - 1 + xx;
                    bool in = ((unsigned)gy < (unsigned)HW) && ((unsigned)gx < (unsigned)HW);
                    if (!in) {
                        u0 = u1 = u2 = u3 = 0.f;
                        v0 = v1 = v2 = v3 = 0.f;
                    }
                }
                u32x2 h0 = { cvt_pk_bf16(u0, u1), cvt_pk_bf16(u2, u3) };
                u32x2 h1v = { cvt_pk_bf16(v0, v1), cvt_pk_bf16(v2, v3) };
                *(u32x2*)(h2b + (px << 6) + wb0) = h0;
                *(u32x2*)(h2b + (px << 6) + wb1) = h1v;
            }
        }
    }
    __syncthreads();

    // ---- phase 3: conv3 MFMA (M=px 256: 16 tiles, 2/wave; N=16 (9 oc); K=288) ----
    {
        const unsigned short* w3e = g_w3b + e * 9 * 16 * 32;
        const int px0 = (wave * 2) * 16 + r16, px1 = (wave * 2 + 1) * 16 + r16;
        const int pb0 = (px0 >> 4) * 18 + (px0 & 15);
        const int pb1 = (px1 >> 4) * 18 + (px1 & 15);
        f32x4 acc0 = {0.f,0.f,0.f,0.f}, acc1 = {0.f,0.f,0.f,0.f};
        #pragma unroll
        for (int s = 0; s < 9; ++s) {
            int d = (s / 3) * 18 + (s % 3);
            int p0 = pb0 + d, p1 = pb1 + d;
            bf16x8s A0 = *(const bf16x8s*)(h2b + ((p0 << 6) | ((g * 16) ^ ((p0 & 3) << 4))));
            bf16x8s A1 = *(const bf16x8s*)(h2b + ((p1 << 6) | ((g * 16) ^ ((p1 & 3) << 4))));
            bf16x8s B = *(const bf16x8s*)(w3e + (s * 16 + r16) * 32 + g * 8);
            acc0 = __builtin_amdgcn_mfma_f32_16x16x32_bf16(A0, B, acc0, 0, 0, 0);
            acc1 = __builtin_amdgcn_mfma_f32_16x16x32_bf16(A1, B, acc1, 0, 0, 0);
        }
        __syncthreads();      // h2b reads done; outT (aliasing h1s) is safe, but
                              // conv3 writes outT which aliases h1s region only.
        if (r16 < C3) {
            float bias = b3[e * C3 + r16];
            const int ocr = r16 / 3, occ = r16 % 3;
            #pragma unroll
            for (int m = 0; m < 2; ++m) {
                f32x4 a = m ? acc1 : acc0;
                #pragma unroll
                for (int q = 0; q < 4; ++q) {
                    int pxd = (wave * 2 + m) * 16 + g * 4 + q;
                    int oy = pxd >> 4, ox = pxd & 15;
                    outT[oy * 3 + ocr][ox * 3 + occ] = a[q] + bias;
                }
            }
        }
    }
    __syncthreads();

    // ---- phase 4: coalesced output write: 48 rows x 12 float4 (192 B/row) ----
    #pragma unroll
    for (int it = 0; it < 2; ++it) {
        int idx = it * 512 + t;
        if (idx < 576) {
            int row = idx / 12, c4 = idx - row * 12;
            f32x4 v = *(const f32x4*)&outT[row][c4 * 4];
            *(f32x4*)&out[(b * OUT_HW + 48 * ty + row) * OUT_HW + 48 * tx + c4 * 4] = v;
        }
    }
}

extern "C" void kernel_launch(void* const* d_in, const int* in_sizes, int n_in,
                              void* d_out, int out_size, void* d_ws, size_t ws_size,
                              hipStream_t stream) {
    const float* x  = (const float*)d_in[0];
    const int*   ci = (const int*)  d_in[1];
    const float* w1 = (const float*)d_in[2];
    const float* b1 = (const float*)d_in[3];
    const float* w2 = (const float*)d_in[4];
    const float* b2 = (const float*)d_in[5];
    const float* w3 = (const float*)d_in[6];
    const float* b3 = (const float*)d_in[7];
    float* out = (float*)d_out;

    {
        const int total = NE * C2 * C1 * 9 + NE * C1 * 32 + NE * 9 * 16 * 32;
        repack_weights_kernel<<<(total + 255) / 256, 256, 0, stream>>>(w1, w2, w3);
    }
    {
        dim3 grid(HW / 16, HW / 16, 32);
        espcn_fused_kernel<<<grid, 512, 0, stream>>>(x, ci, b1, b2, b3, out);
    }
}